// Round 4
// baseline (1015.238 us; speedup 1.0000x reference)
//
#include <hip/hip_runtime.h>
#include <hip/hip_bf16.h>
#include <math.h>

#define D 256
#define FT_STRIDE 72   // shorts; 144 B = 16B-aligned rows, banks tile uniformly

typedef short v8s __attribute__((ext_vector_type(8)));
typedef float f32x4 __attribute__((ext_vector_type(4)));

__device__ __forceinline__ unsigned short f2b(float f) {
    return __bfloat16_as_ushort(__float2bfloat16(f));
}
__device__ __forceinline__ float b2f(unsigned short u) {
    return __bfloat162float(__ushort_as_bfloat16(u));
}

// ---------------- K0: segment offsets via binary search on sorted batch ----
__global__ void segstart_kernel(const int* __restrict__ batch, int* __restrict__ seg_start,
                                int N, int B) {
    int b = blockIdx.x * blockDim.x + threadIdx.x;
    if (b > B) return;
    int lo = 0, hi = N;
    while (lo < hi) {
        int mid = (lo + hi) >> 1;
        if (batch[mid] < b) lo = mid + 1; else hi = mid;
    }
    seg_start[b] = lo;
}

// ---------------- K1: gate = x.Wg + bg, emit bf16 copy of x ----------------
template<bool CONV>
__global__ __launch_bounds__(256) void gate_conv_kernel(
    const float* __restrict__ x, const float* __restrict__ Wg,
    const float* __restrict__ bg, float* __restrict__ gate,
    unsigned short* __restrict__ xb16, int N) {
    const int lane = threadIdx.x & 63;
    const int wid = blockIdx.x * 4 + (threadIdx.x >> 6);
    const int nw = gridDim.x * 4;
    const float4 wv = *(const float4*)(Wg + lane * 4);
    const float bgv = bg[0];
    for (int n = wid; n < N; n += nw) {
        const float4 xv = *(const float4*)(x + (size_t)n * D + lane * 4);
        if (CONV) {
            ushort4 h = { f2b(xv.x), f2b(xv.y), f2b(xv.z), f2b(xv.w) };
            *(ushort4*)(xb16 + (size_t)n * D + lane * 4) = h;
        }
        float d = xv.x * wv.x + xv.y * wv.y + xv.z * wv.z + xv.w * wv.w;
        #pragma unroll
        for (int off = 32; off; off >>= 1) d += __shfl_xor(d, off, 64);
        if (lane == 0) gate[n] = d + bgv;
    }
}

// ---------------- K1b: per-graph softmax stats (max, 1/sum) ----------------
__global__ __launch_bounds__(256) void stats_kernel(const float* __restrict__ gate,
                                                    const int* __restrict__ seg_start,
                                                    float* __restrict__ mvec,
                                                    float* __restrict__ invs, int B) {
    int wid = blockIdx.x * 4 + (threadIdx.x >> 6);
    int lane = threadIdx.x & 63;
    if (wid >= B) return;
    int s0 = seg_start[wid], s1 = seg_start[wid + 1];
    float m = -INFINITY;
    for (int i = s0 + lane; i < s1; i += 64) m = fmaxf(m, gate[i]);
    #pragma unroll
    for (int off = 32; off > 0; off >>= 1) m = fmaxf(m, __shfl_xor(m, off, 64));
    float s = 0.f;
    for (int i = s0 + lane; i < s1; i += 64) s += __expf(gate[i] - m);
    #pragma unroll
    for (int off = 32; off > 0; off >>= 1) s += __shfl_xor(s, off, 64);
    if (lane == 0) { mvec[wid] = m; invs[wid] = (s > 0.f) ? 1.f / s : 0.f; }
}

// ---------------- W -> bf16 in MFMA B-fragment order (K x 256) -------------
// B frag (16x16x32): W[k][n] at lane = ((k>>3)&3)*16 + (n&15), reg j = k&7.
__global__ void wconv_kernel(const float* __restrict__ Wf, unsigned short* __restrict__ Wb,
                             int K) {
    int idx = blockIdx.x * 256 + threadIdx.x;
    int k = idx >> 8, n = idx & 255;
    if (k >= K) return;
    int n_tile = n >> 4, k_step = k >> 5, ksteps = K >> 5;
    int lane = ((k >> 3) & 3) * 16 + (n & 15);
    int j = k & 7;
    int dst = (((n_tile * ksteps + k_step) * 64) + lane) * 8 + j;
    Wb[dst] = f2b(Wf[k * 256 + n]);
}

// ---------------- K2: MFMA feat GEMM fused with softmax-weighted segsum ----
// Block = 64 nodes x 256 cols; 4 waves, wave w owns cols [w*64, w*64+64).
template<bool BF16IN>
__global__ __launch_bounds__(256) void feat_attn_kernel(
    const float* __restrict__ x, const unsigned short* __restrict__ xb16,
    const unsigned short* __restrict__ Wb,
    const float* __restrict__ bfeat, const float* __restrict__ gate,
    const int* __restrict__ batch, const float* __restrict__ mvec,
    const float* __restrict__ invs, float* __restrict__ xg, int N) {

    // transposed: feat_s[col][node], stride 72 shorts (144 B, 16B-aligned)
    __shared__ unsigned short feat_s[256 * FT_STRIDE] __attribute__((aligned(16)));
    __shared__ float alpha_s[64];
    __shared__ int batch_s[64];

    const int tid = threadIdx.x;
    const int n0 = blockIdx.x * 64;
    const int cnt = min(64, N - n0);

    if (tid < 64) {
        if (tid < cnt) {
            int n = n0 + tid;
            int b = batch[n];
            batch_s[tid] = b;
            alpha_s[tid] = __expf(gate[n] - mvec[b]) * invs[b];
        } else { batch_s[tid] = -1; alpha_s[tid] = 0.f; }
    }

    const int w = tid >> 6, lane = tid & 63;
    const int mrow = lane & 15, q = lane >> 4;

    f32x4 acc[4][4];
    #pragma unroll
    for (int i = 0; i < 4; i++)
        #pragma unroll
        for (int j = 0; j < 4; j++) acc[i][j] = (f32x4){0.f, 0.f, 0.f, 0.f};

    size_t rowbase[4];
    #pragma unroll
    for (int rb = 0; rb < 4; rb++) {
        int r = n0 + rb * 16 + mrow;
        if (r > N - 1) r = N - 1;
        rowbase[rb] = (size_t)r * D + q * 8;
    }

    v8s a_cur[4], b_cur[4], a_nxt[4], b_nxt[4];
    #pragma unroll
    for (int rb = 0; rb < 4; rb++)
        a_cur[rb] = *(const v8s*)(xb16 + rowbase[rb]);
    #pragma unroll
    for (int cb = 0; cb < 4; cb++)
        b_cur[cb] = *(const v8s*)(Wb + (((size_t)(w * 4 + cb) * 8 + 0) * 64 + lane) * 8);

    #pragma unroll
    for (int ks = 0; ks < 8; ks++) {
        if (ks < 7) {
            #pragma unroll
            for (int rb = 0; rb < 4; rb++)
                a_nxt[rb] = *(const v8s*)(xb16 + rowbase[rb] + (ks + 1) * 32);
            #pragma unroll
            for (int cb = 0; cb < 4; cb++)
                b_nxt[cb] = *(const v8s*)(Wb + (((size_t)(w * 4 + cb) * 8 + ks + 1) * 64 + lane) * 8);
        }
        #pragma unroll
        for (int rb = 0; rb < 4; rb++)
            #pragma unroll
            for (int cb = 0; cb < 4; cb++)
                acc[rb][cb] = __builtin_amdgcn_mfma_f32_16x16x32_bf16(
                    a_cur[rb], b_cur[cb], acc[rb][cb], 0, 0, 0);
        #pragma unroll
        for (int i = 0; i < 4; i++) { a_cur[i] = a_nxt[i]; b_cur[i] = b_nxt[i]; }
    }

    // epilogue: bias + leaky -> bf16, transposed LDS, b64 packed writes
    // C/D layout: col = lane&15, row = q*4 + reg (within 16x16 tile)
    #pragma unroll
    for (int cb = 0; cb < 4; cb++) {
        int col = w * 64 + cb * 16 + mrow;
        float bias = bfeat[col];
        #pragma unroll
        for (int rb = 0; rb < 4; rb++) {
            ushort4 h;
            float y0 = acc[rb][cb][0] + bias; y0 = (y0 >= 0.f) ? y0 : 0.01f * y0;
            float y1 = acc[rb][cb][1] + bias; y1 = (y1 >= 0.f) ? y1 : 0.01f * y1;
            float y2 = acc[rb][cb][2] + bias; y2 = (y2 >= 0.f) ? y2 : 0.01f * y2;
            float y3 = acc[rb][cb][3] + bias; y3 = (y3 >= 0.f) ? y3 : 0.01f * y3;
            h.x = f2b(y0); h.y = f2b(y1); h.z = f2b(y2); h.w = f2b(y3);
            *(ushort4*)(&feat_s[col * FT_STRIDE + rb * 16 + q * 4]) = h;
        }
    }
    __syncthreads();

    // walk: thread tid owns col tid; 8x ds_read_b128 instead of 64x u16
    float sum = 0.f;
    int cur = batch_s[0];
    for (int i0 = 0; i0 < cnt; i0 += 8) {
        v8s f = *(const v8s*)(&feat_s[tid * FT_STRIDE + i0]);
        #pragma unroll
        for (int j = 0; j < 8; j++) {
            int i = i0 + j;
            if (i >= cnt) break;
            int b = batch_s[i];
            if (b != cur) {
                atomicAdd(&xg[(size_t)cur * D + tid], sum);
                sum = 0.f; cur = b;
            }
            sum = fmaf(alpha_s[i], b2f((unsigned short)f[j]), sum);
        }
    }
    atomicAdd(&xg[(size_t)cur * D + tid], sum);
}

// ---------------- K3 (MFMA, fused cat conversion) --------------------------
// out = leaky([xg, xg_old] @ W_t + b_t) + xg_old
__global__ __launch_bounds__(256) void out_mfma_kernel(
    const float* __restrict__ xg, const float* __restrict__ xg_old,
    const unsigned short* __restrict__ Wtb, const float* __restrict__ bt,
    float* __restrict__ out, int B) {
    const int tid = threadIdx.x;
    const int w = tid >> 6, lane = tid & 63, mrow = lane & 15, q = lane >> 4;
    const int r0 = blockIdx.x * 64;

    f32x4 acc[4][4];
    #pragma unroll
    for (int i = 0; i < 4; i++)
        #pragma unroll
        for (int j = 0; j < 4; j++) acc[i][j] = (f32x4){0.f, 0.f, 0.f, 0.f};

    size_t rowbase[4];
    #pragma unroll
    for (int rb = 0; rb < 4; rb++) {
        int r = r0 + rb * 16 + mrow;
        if (r > B - 1) r = B - 1;
        rowbase[rb] = (size_t)r * D + q * 8;
    }

    #pragma unroll
    for (int ks = 0; ks < 16; ks++) {
        v8s a[4], bfr[4];
        #pragma unroll
        for (int rb = 0; rb < 4; rb++) {
            const float* src = (ks < 8) ? (xg + rowbase[rb] + ks * 32)
                                        : (xg_old + rowbase[rb] + (ks - 8) * 32);
            float4 f0 = *(const float4*)src;
            float4 f1 = *(const float4*)(src + 4);
            v8s v;
            v[0] = (short)f2b(f0.x); v[1] = (short)f2b(f0.y);
            v[2] = (short)f2b(f0.z); v[3] = (short)f2b(f0.w);
            v[4] = (short)f2b(f1.x); v[5] = (short)f2b(f1.y);
            v[6] = (short)f2b(f1.z); v[7] = (short)f2b(f1.w);
            a[rb] = v;
        }
        #pragma unroll
        for (int cb = 0; cb < 4; cb++)
            bfr[cb] = *(const v8s*)(Wtb + (((size_t)(w * 4 + cb) * 16 + ks) * 64 + lane) * 8);
        #pragma unroll
        for (int rb = 0; rb < 4; rb++)
            #pragma unroll
            for (int cb = 0; cb < 4; cb++)
                acc[rb][cb] = __builtin_amdgcn_mfma_f32_16x16x32_bf16(
                    a[rb], bfr[cb], acc[rb][cb], 0, 0, 0);
    }

    #pragma unroll
    for (int cb = 0; cb < 4; cb++) {
        int col = w * 64 + cb * 16 + mrow;
        float bias = bt[col];
        #pragma unroll
        for (int rb = 0; rb < 4; rb++) {
            #pragma unroll
            for (int reg = 0; reg < 4; reg++) {
                int row = r0 + rb * 16 + q * 4 + reg;
                if (row < B) {
                    float y = acc[rb][cb][reg] + bias;
                    y = (y >= 0.f) ? y : 0.01f * y;
                    out[(size_t)row * D + col] = y + xg_old[(size_t)row * D + col];
                }
            }
        }
    }
}

// ---------------- K3 (fp32 fallback) ---------------------------------------
__global__ __launch_bounds__(256) void out_kernel(
    const float* __restrict__ xg, const float* __restrict__ xg_old,
    const float* __restrict__ Wt, const float* __restrict__ bt,
    float* __restrict__ out) {
    const int t = threadIdx.x;
    const int r0 = blockIdx.x * 8;
    float acc[8];
    #pragma unroll
    for (int r = 0; r < 8; r++) acc[r] = 0.f;
    for (int k = 0; k < D; k++) {
        const float w = Wt[k * D + t];
        #pragma unroll
        for (int r = 0; r < 8; r++)
            acc[r] = fmaf(xg[(size_t)(r0 + r) * D + k], w, acc[r]);
    }
    for (int k = 0; k < D; k++) {
        const float w = Wt[(D + k) * D + t];
        #pragma unroll
        for (int r = 0; r < 8; r++)
            acc[r] = fmaf(xg_old[(size_t)(r0 + r) * D + k], w, acc[r]);
    }
    const float btt = bt[t];
    #pragma unroll
    for (int r = 0; r < 8; r++) {
        float y = acc[r] + btt;
        y = (y >= 0.f) ? y : 0.01f * y;
        out[(size_t)(r0 + r) * D + t] = y + xg_old[(size_t)(r0 + r) * D + t];
    }
}

// ---------------------------------------------------------------------------
extern "C" void kernel_launch(void* const* d_in, const int* in_sizes, int n_in,
                              void* d_out, int out_size, void* d_ws, size_t ws_size,
                              hipStream_t stream) {
    const float* xg_old = (const float*)d_in[0];   // [B, D]
    const float* x      = (const float*)d_in[1];   // [N, D]
    const int*   batch  = (const int*)d_in[2];     // [N], sorted
    const float* W_gate = (const float*)d_in[3];   // [D]
    const float* b_gate = (const float*)d_in[4];   // [1]
    const float* W_feat = (const float*)d_in[5];   // [D, D]
    const float* b_feat = (const float*)d_in[6];   // [D]
    const float* W_t    = (const float*)d_in[7];   // [2D, D]
    const float* b_t    = (const float*)d_in[8];   // [D]
    float* out = (float*)d_out;                    // [B, D]

    const int N = in_sizes[1] / D;                 // 500000
    const int B = in_sizes[0] / D;                 // 10000

    // workspace layout
    char* ws = (char*)d_ws;
    int*            seg_start = (int*)ws;                         // 40 KB
    float*          gate      = (float*)(ws + 0x10000);           // 2 MB
    float*          mvec      = (float*)(ws + 0x220000);          // 40 KB
    float*          invs      = (float*)(ws + 0x230000);          // 40 KB
    unsigned short* Wb        = (unsigned short*)(ws + 0x240000); // 128 KB
    unsigned short* Wtb       = (unsigned short*)(ws + 0x260000); // 256 KB
    float*          xg        = (float*)(ws + 0x2A0000);          // 10.24 MB
    unsigned short* xb16      = (unsigned short*)(ws + 0xCA0000); // 256 MB

    const size_t need_full = 0xCA0000 + (size_t)N * D * 2;        // ~269 MB
    const size_t need_mid  = 0xCA0000;
    const bool full = ws_size >= need_full;
    const bool mid  = ws_size >= need_mid;

    segstart_kernel<<<(B + 1 + 255) / 256, 256, 0, stream>>>(batch, seg_start, N, B);
    if (full)
        gate_conv_kernel<true><<<2048, 256, 0, stream>>>(x, W_gate, b_gate, gate, xb16, N);
    else
        gate_conv_kernel<false><<<2048, 256, 0, stream>>>(x, W_gate, b_gate, gate, xb16, N);
    stats_kernel<<<(B + 3) / 4, 256, 0, stream>>>(gate, seg_start, mvec, invs, B);
    wconv_kernel<<<256, 256, 0, stream>>>(W_feat, Wb, 256);
    if (mid) wconv_kernel<<<512, 256, 0, stream>>>(W_t, Wtb, 512);
    hipMemsetAsync(xg, 0, (size_t)B * D * sizeof(float), stream);

    if (full)
        feat_attn_kernel<true><<<(N + 63) / 64, 256, 0, stream>>>(
            x, xb16, Wb, b_feat, gate, batch, mvec, invs, xg, N);
    else
        feat_attn_kernel<false><<<(N + 63) / 64, 256, 0, stream>>>(
            x, xb16, Wb, b_feat, gate, batch, mvec, invs, xg, N);

    if (mid)
        out_mfma_kernel<<<(B + 63) / 64, 256, 0, stream>>>(xg, xg_old, Wtb, b_t, out, B);
    else
        out_kernel<<<B / 8, 256, 0, stream>>>(xg, xg_old, W_t, b_t, out);
}

// Round 5
// 952.245 us; speedup vs baseline: 1.0662x; 1.0662x over previous
//
#include <hip/hip_runtime.h>
#include <hip/hip_bf16.h>
#include <math.h>

#define D 256
#define FT_STRIDE 72   // shorts; 144 B rows, 16B-aligned; b128 walk reads hit the 8-clk floor

typedef short v8s __attribute__((ext_vector_type(8)));
typedef float f32x4 __attribute__((ext_vector_type(4)));
typedef float f32x16 __attribute__((ext_vector_type(16)));

__device__ __forceinline__ unsigned short f2b(float f) {
    return __bfloat16_as_ushort(__float2bfloat16(f));
}
__device__ __forceinline__ float b2f(unsigned short u) {
    return __bfloat162float(__ushort_as_bfloat16(u));
}

// ---------------- prep: segstart + wconv(Wf,32x32) + wconv(Wt,16x16) + zero xg
// one dispatch, block ranges do different jobs
__global__ void prep_kernel(const int* __restrict__ batch, int* __restrict__ seg_start,
                            const float* __restrict__ Wf, unsigned short* __restrict__ Wb32,
                            const float* __restrict__ Wt, unsigned short* __restrict__ Wtb,
                            float* __restrict__ xg, int N, int B) {
    const int blk = blockIdx.x, tid = threadIdx.x;
    if (blk < 40) {
        int b = blk * 256 + tid;
        if (b > B) return;
        int lo = 0, hi = N;
        while (lo < hi) {
            int mid = (lo + hi) >> 1;
            if (batch[mid] < b) lo = mid + 1; else hi = mid;
        }
        seg_start[b] = lo;
    } else if (blk < 296) {
        // W_feat -> 32x32x16 B-frag order: B[k][n]: lane=((k>>3)&1)*32+(n&31), j=k&7
        int idx = (blk - 40) * 256 + tid;         // 65536
        int k = idx >> 8, n = idx & 255;
        int lane = ((k >> 3) & 1) * 32 + (n & 31);
        int j = k & 7, kst = k >> 4, ntile = n >> 5;
        Wb32[(((ntile * 16 + kst) * 64) + lane) * 8 + j] = f2b(Wf[k * 256 + n]);
    } else if (blk < 808) {
        // W_t -> 16x16x32 B-frag order (K=512): lane=((k>>3)&3)*16+(n&15), j=k&7
        int idx = (blk - 296) * 256 + tid;        // 131072
        int k = idx >> 8, n = idx & 255;
        int ntile = n >> 4, kst = k >> 5;
        int lane = ((k >> 3) & 3) * 16 + (n & 15);
        int j = k & 7;
        Wtb[(((ntile * 16 + kst) * 64) + lane) * 8 + j] = f2b(Wt[k * 256 + n]);
    } else {
        int idx = (blk - 808) * 256 + tid;        // 640000 float4 = 10.24 MB
        if (idx < 640000) ((float4*)xg)[idx] = make_float4(0.f, 0.f, 0.f, 0.f);
    }
}

// ---------------- K1: gate = x.Wg + bg, emit bf16 copy of x; 2 rows/iter ---
template<bool CONV>
__global__ __launch_bounds__(256) void gate_conv_kernel(
    const float* __restrict__ x, const float* __restrict__ Wg,
    const float* __restrict__ bg, float* __restrict__ gate,
    unsigned short* __restrict__ xb16, int N) {
    const int lane = threadIdx.x & 63;
    const int wid = blockIdx.x * 4 + (threadIdx.x >> 6);
    const int nw = gridDim.x * 4;
    const float4 wv = *(const float4*)(Wg + lane * 4);
    const float bgv = bg[0];
    // N is even; pairs (n, n+1) both valid whenever n < N
    for (int n = wid * 2; n < N; n += nw * 2) {
        const float4 xv0 = *(const float4*)(x + (size_t)n * D + lane * 4);
        const float4 xv1 = *(const float4*)(x + (size_t)(n + 1) * D + lane * 4);
        if (CONV) {
            ushort4 h0 = { f2b(xv0.x), f2b(xv0.y), f2b(xv0.z), f2b(xv0.w) };
            ushort4 h1 = { f2b(xv1.x), f2b(xv1.y), f2b(xv1.z), f2b(xv1.w) };
            *(ushort4*)(xb16 + (size_t)n * D + lane * 4) = h0;
            *(ushort4*)(xb16 + (size_t)(n + 1) * D + lane * 4) = h1;
        }
        float d0 = xv0.x * wv.x + xv0.y * wv.y + xv0.z * wv.z + xv0.w * wv.w;
        float d1 = xv1.x * wv.x + xv1.y * wv.y + xv1.z * wv.z + xv1.w * wv.w;
        #pragma unroll
        for (int off = 32; off; off >>= 1) {
            d0 += __shfl_xor(d0, off, 64);
            d1 += __shfl_xor(d1, off, 64);
        }
        if (lane == 0) { gate[n] = d0 + bgv; gate[n + 1] = d1 + bgv; }
    }
}

// ---------------- K1b: per-graph softmax stats (max, 1/sum) ----------------
__global__ __launch_bounds__(256) void stats_kernel(const float* __restrict__ gate,
                                                    const int* __restrict__ seg_start,
                                                    float* __restrict__ mvec,
                                                    float* __restrict__ invs, int B) {
    int wid = blockIdx.x * 4 + (threadIdx.x >> 6);
    int lane = threadIdx.x & 63;
    if (wid >= B) return;
    int s0 = seg_start[wid], s1 = seg_start[wid + 1];
    float m = -INFINITY;
    for (int i = s0 + lane; i < s1; i += 64) m = fmaxf(m, gate[i]);
    #pragma unroll
    for (int off = 32; off > 0; off >>= 1) m = fmaxf(m, __shfl_xor(m, off, 64));
    float s = 0.f;
    for (int i = s0 + lane; i < s1; i += 64) s += __expf(gate[i] - m);
    #pragma unroll
    for (int off = 32; off > 0; off >>= 1) s += __shfl_xor(s, off, 64);
    if (lane == 0) { mvec[wid] = m; invs[wid] = (s > 0.f) ? 1.f / s : 0.f; }
}

// ---------------- K2: 32x32x16-MFMA feat GEMM + softmax-weighted segsum ----
// Block = 64 nodes x 256 cols; wave w owns cols [w*64, w*64+64) as 2 tiles of 32.
// A-pipeline: 3 slots, distance 2 (HBM ~900cyc); B: 2 slots, distance 1 (L2).
template<bool BF16IN>
__global__ __launch_bounds__(256, 4) void feat_attn_kernel(
    const float* __restrict__ x, const unsigned short* __restrict__ xb16,
    const unsigned short* __restrict__ Wb32,
    const float* __restrict__ bfeat, const float* __restrict__ gate,
    const int* __restrict__ batch, const float* __restrict__ mvec,
    const float* __restrict__ invs, float* __restrict__ xg, int N) {

    __shared__ unsigned short feat_s[256 * FT_STRIDE] __attribute__((aligned(16)));
    __shared__ float alpha_s[64];
    __shared__ int batch_s[64];

    const int tid = threadIdx.x;
    const int n0 = blockIdx.x * 64;

    if (tid < 64) {
        int n = n0 + tid;
        if (n < N) {
            int b = batch[n];
            batch_s[tid] = b;
            alpha_s[tid] = __expf(gate[n] - mvec[b]) * invs[b];
        } else {            // pad with last valid segment, zero weight
            batch_s[tid] = batch[N - 1];
            alpha_s[tid] = 0.f;
        }
    }

    const int w = tid >> 6, lane = tid & 63;
    const int l31 = lane & 31, lh = lane >> 5;

    f32x16 acc[2][2];
    #pragma unroll
    for (int i = 0; i < 2; i++)
        #pragma unroll
        for (int j = 0; j < 2; j++)
            #pragma unroll
            for (int e = 0; e < 16; e++) acc[i][j][e] = 0.f;

    size_t abase[2];
    #pragma unroll
    for (int rt = 0; rt < 2; rt++) {
        int r = n0 + rt * 32 + l31;
        if (r > N - 1) r = N - 1;
        abase[rt] = (size_t)r * D + lh * 8;
    }

    v8s A[3][2], Bf[2][2];
    #pragma unroll
    for (int p = 0; p < 2; p++) {
        #pragma unroll
        for (int rt = 0; rt < 2; rt++) {
            if (BF16IN) A[p][rt] = *(const v8s*)(xb16 + abase[rt] + p * 16);
            else {
                const float* src = x + abase[rt] + p * 16;
                float4 f0 = *(const float4*)src, f1 = *(const float4*)(src + 4);
                v8s v; v[0]=(short)f2b(f0.x); v[1]=(short)f2b(f0.y);
                v[2]=(short)f2b(f0.z); v[3]=(short)f2b(f0.w);
                v[4]=(short)f2b(f1.x); v[5]=(short)f2b(f1.y);
                v[6]=(short)f2b(f1.z); v[7]=(short)f2b(f1.w);
                A[p][rt] = v;
            }
        }
        #pragma unroll
        for (int ct = 0; ct < 2; ct++)
            Bf[p][ct] = *(const v8s*)(Wb32 + (((size_t)(w * 2 + ct) * 16 + p) * 64 + lane) * 8);
    }

    #pragma unroll
    for (int ks = 0; ks < 16; ks++) {
        const int cs = ks % 3, bs = ks & 1;
        if (ks < 14) {
            const int ns = (ks + 2) % 3;
            #pragma unroll
            for (int rt = 0; rt < 2; rt++) {
                if (BF16IN) A[ns][rt] = *(const v8s*)(xb16 + abase[rt] + (ks + 2) * 16);
                else {
                    const float* src = x + abase[rt] + (ks + 2) * 16;
                    float4 f0 = *(const float4*)src, f1 = *(const float4*)(src + 4);
                    v8s v; v[0]=(short)f2b(f0.x); v[1]=(short)f2b(f0.y);
                    v[2]=(short)f2b(f0.z); v[3]=(short)f2b(f0.w);
                    v[4]=(short)f2b(f1.x); v[5]=(short)f2b(f1.y);
                    v[6]=(short)f2b(f1.z); v[7]=(short)f2b(f1.w);
                    A[ns][rt] = v;
                }
            }
        }
        if (ks < 15) {
            const int nb = (ks + 1) & 1;
            #pragma unroll
            for (int ct = 0; ct < 2; ct++)
                Bf[nb][ct] = *(const v8s*)(Wb32 + (((size_t)(w * 2 + ct) * 16 + ks + 1) * 64 + lane) * 8);
        }
        #pragma unroll
        for (int rt = 0; rt < 2; rt++)
            #pragma unroll
            for (int ct = 0; ct < 2; ct++)
                acc[rt][ct] = __builtin_amdgcn_mfma_f32_32x32x16_bf16(
                    A[cs][rt], Bf[bs][ct], acc[rt][ct], 0, 0, 0);
    }

    __syncthreads();   // alpha_s/batch_s visible before epilogue reads

    // epilogue: bias + leaky + alpha premult -> bf16 transposed LDS
    // C/D 32x32: col=lane&31, row=(reg&3)+8*(reg>>2)+4*(lane>>5)
    #pragma unroll
    for (int ct = 0; ct < 2; ct++) {
        int col = w * 64 + ct * 32 + l31;
        float bias = bfeat[col];
        #pragma unroll
        for (int rt = 0; rt < 2; rt++) {
            #pragma unroll
            for (int g = 0; g < 4; g++) {
                int rbase = rt * 32 + g * 8 + 4 * lh;
                ushort4 h;
                #pragma unroll
                for (int rr = 0; rr < 4; rr++) {
                    float y = acc[rt][ct][g * 4 + rr] + bias;
                    y = (y >= 0.f) ? y : 0.01f * y;
                    y *= alpha_s[rbase + rr];
                    ((unsigned short*)&h)[rr] = f2b(y);
                }
                *(ushort4*)(&feat_s[col * FT_STRIDE + rbase]) = h;
            }
        }
    }
    __syncthreads();

    // walk: thread tid owns col tid; values already alpha-weighted -> tree sums
    float sum = 0.f;
    int cur = batch_s[0];
    #pragma unroll
    for (int i0 = 0; i0 < 64; i0 += 8) {
        v8s f = *(const v8s*)(&feat_s[tid * FT_STRIDE + i0]);
        int b0 = batch_s[i0], b7 = batch_s[i0 + 7];
        if (b0 == b7) {                 // no boundary in group (common)
            if (b0 != cur) {
                atomicAdd(&xg[(size_t)cur * D + tid], sum);
                sum = 0.f; cur = b0;
            }
            float p0 = b2f((unsigned short)f[0]) + b2f((unsigned short)f[1]);
            float p1 = b2f((unsigned short)f[2]) + b2f((unsigned short)f[3]);
            float p2 = b2f((unsigned short)f[4]) + b2f((unsigned short)f[5]);
            float p3 = b2f((unsigned short)f[6]) + b2f((unsigned short)f[7]);
            sum += (p0 + p1) + (p2 + p3);
        } else {
            #pragma unroll
            for (int j = 0; j < 8; j++) {
                int b = batch_s[i0 + j];
                if (b != cur) {
                    atomicAdd(&xg[(size_t)cur * D + tid], sum);
                    sum = 0.f; cur = b;
                }
                sum += b2f((unsigned short)f[j]);
            }
        }
    }
    atomicAdd(&xg[(size_t)cur * D + tid], sum);
}

// ---------------- K3 (MFMA, fused cat conversion) --------------------------
__global__ __launch_bounds__(256) void out_mfma_kernel(
    const float* __restrict__ xg, const float* __restrict__ xg_old,
    const unsigned short* __restrict__ Wtb, const float* __restrict__ bt,
    float* __restrict__ out, int B) {
    const int tid = threadIdx.x;
    const int w = tid >> 6, lane = tid & 63, mrow = lane & 15, q = lane >> 4;
    const int r0 = blockIdx.x * 64;

    f32x4 acc[4][4];
    #pragma unroll
    for (int i = 0; i < 4; i++)
        #pragma unroll
        for (int j = 0; j < 4; j++) acc[i][j] = (f32x4){0.f, 0.f, 0.f, 0.f};

    size_t rowbase[4];
    #pragma unroll
    for (int rb = 0; rb < 4; rb++) {
        int r = r0 + rb * 16 + mrow;
        if (r > B - 1) r = B - 1;
        rowbase[rb] = (size_t)r * D + q * 8;
    }

    #pragma unroll
    for (int ks = 0; ks < 16; ks++) {
        v8s a[4], bfr[4];
        #pragma unroll
        for (int rb = 0; rb < 4; rb++) {
            const float* src = (ks < 8) ? (xg + rowbase[rb] + ks * 32)
                                        : (xg_old + rowbase[rb] + (ks - 8) * 32);
            float4 f0 = *(const float4*)src;
            float4 f1 = *(const float4*)(src + 4);
            v8s v;
            v[0] = (short)f2b(f0.x); v[1] = (short)f2b(f0.y);
            v[2] = (short)f2b(f0.z); v[3] = (short)f2b(f0.w);
            v[4] = (short)f2b(f1.x); v[5] = (short)f2b(f1.y);
            v[6] = (short)f2b(f1.z); v[7] = (short)f2b(f1.w);
            a[rb] = v;
        }
        #pragma unroll
        for (int cb = 0; cb < 4; cb++)
            bfr[cb] = *(const v8s*)(Wtb + (((size_t)(w * 4 + cb) * 16 + ks) * 64 + lane) * 8);
        #pragma unroll
        for (int rb = 0; rb < 4; rb++)
            #pragma unroll
            for (int cb = 0; cb < 4; cb++)
                acc[rb][cb] = __builtin_amdgcn_mfma_f32_16x16x32_bf16(
                    a[rb], bfr[cb], acc[rb][cb], 0, 0, 0);
    }

    #pragma unroll
    for (int cb = 0; cb < 4; cb++) {
        int col = w * 64 + cb * 16 + mrow;
        float bias = bt[col];
        #pragma unroll
        for (int rb = 0; rb < 4; rb++) {
            #pragma unroll
            for (int reg = 0; reg < 4; reg++) {
                int row = r0 + rb * 16 + q * 4 + reg;
                if (row < B) {
                    float y = acc[rb][cb][reg] + bias;
                    y = (y >= 0.f) ? y : 0.01f * y;
                    out[(size_t)row * D + col] = y + xg_old[(size_t)row * D + col];
                }
            }
        }
    }
}

// ---------------------------------------------------------------------------
extern "C" void kernel_launch(void* const* d_in, const int* in_sizes, int n_in,
                              void* d_out, int out_size, void* d_ws, size_t ws_size,
                              hipStream_t stream) {
    const float* xg_old = (const float*)d_in[0];   // [B, D]
    const float* x      = (const float*)d_in[1];   // [N, D]
    const int*   batch  = (const int*)d_in[2];     // [N], sorted
    const float* W_gate = (const float*)d_in[3];   // [D]
    const float* b_gate = (const float*)d_in[4];   // [1]
    const float* W_feat = (const float*)d_in[5];   // [D, D]
    const float* b_feat = (const float*)d_in[6];   // [D]
    const float* W_t    = (const float*)d_in[7];   // [2D, D]
    const float* b_t    = (const float*)d_in[8];   // [D]
    float* out = (float*)d_out;                    // [B, D]

    const int N = in_sizes[1] / D;                 // 500000
    const int B = in_sizes[0] / D;                 // 10000

    // workspace layout
    char* ws = (char*)d_ws;
    int*            seg_start = (int*)ws;                         // 40 KB
    float*          gate      = (float*)(ws + 0x10000);           // 2 MB
    float*          mvec      = (float*)(ws + 0x220000);          // 40 KB
    float*          invs      = (float*)(ws + 0x230000);          // 40 KB
    unsigned short* Wb32      = (unsigned short*)(ws + 0x240000); // 128 KB
    unsigned short* Wtb       = (unsigned short*)(ws + 0x260000); // 256 KB
    float*          xg        = (float*)(ws + 0x2A0000);          // 10.24 MB
    unsigned short* xb16      = (unsigned short*)(ws + 0xCA0000); // 256 MB

    const size_t need_full = 0xCA0000 + (size_t)N * D * 2;        // ~269 MB
    const bool full = ws_size >= need_full;

    prep_kernel<<<3308, 256, 0, stream>>>(batch, seg_start, W_feat, Wb32, W_t, Wtb, xg, N, B);
    if (full)
        gate_conv_kernel<true><<<2048, 256, 0, stream>>>(x, W_gate, b_gate, gate, xb16, N);
    else
        gate_conv_kernel<false><<<2048, 256, 0, stream>>>(x, W_gate, b_gate, gate, xb16, N);
    stats_kernel<<<(B + 3) / 4, 256, 0, stream>>>(gate, seg_start, mvec, invs, B);

    if (full)
        feat_attn_kernel<true><<<(N + 63) / 64, 256, 0, stream>>>(
            x, xb16, Wb32, b_feat, gate, batch, mvec, invs, xg, N);
    else
        feat_attn_kernel<false><<<(N + 63) / 64, 256, 0, stream>>>(
            x, xb16, Wb32, b_feat, gate, batch, mvec, invs, xg, N);

    out_mfma_kernel<<<(B + 63) / 64, 256, 0, stream>>>(xg, xg_old, Wtb, b_t, out, B);
}